// Round 7
// baseline (384.856 us; speedup 1.0000x reference)
//
#include <hip/hip_runtime.h>
#include <math.h>

#define NPTS 65536
#define NS   2048
#define C2   256
#define C3   128

// ---- workspace layout (byte offsets) ----
#define WS_SORT    0          // float4[2048] grid-sorted centres (x,y,z,|c|^2) : 32768
#define WS_P2T     32768      // bf16 [2048][256]          : 1048576
#define WS_W0F     1081344    // bf16 frag [10][16][64][8] : 163840
#define WS_W1F     1245184    // bf16 frag [8][8][64][8]   : 65536
#define WS_AB0     1310720    // float A0[256],B0[256]
#define WS_AB1     1312768    // float A1[128],B1[128]
#define WS_KIDX    1313792    // int [65536][3]
#define WS_KW      2100224    // float [65536][3]
#define WS_CSTART  2886656    // u16[1001] CSR starts
#define WS_SIDX    2888704    // u16[2048] sorted->orig idx
#define WS_FCNT    2892800    // u32 fallback count
#define WS_FLIST   2892816    // int[65536] fallback point ids

typedef __attribute__((ext_vector_type(8))) short bf16x8;
typedef __attribute__((ext_vector_type(4))) float f32x4;

__device__ __forceinline__ unsigned short f2bf(float f) {
  unsigned u = __builtin_bit_cast(unsigned, f);
  u = (u + 0x7FFFu + ((u >> 16) & 1u)) >> 16;
  return (unsigned short)u;
}
__device__ __forceinline__ float bf2f(unsigned h) {
  return __builtin_bit_cast(float, h << 16);
}

// Gaussian decile edges (partition correctness does not depend on exact values;
// build & query use the SAME constants).
#define GE0 -1.2815516f
#define GE1 -0.84162123f
#define GE2 -0.52440051f
#define GE3 -0.25334710f
#define GE4  0.0f
#define GE5  0.25334710f
#define GE6  0.52440051f
#define GE7  0.84162123f
#define GE8  1.2815516f

__device__ __forceinline__ int cls9(float v) {
  int c = 0;
  c += v > GE0; c += v > GE1; c += v > GE2; c += v > GE3; c += v > GE4;
  c += v > GE5; c += v > GE6; c += v > GE7; c += v > GE8;
  return c;
}
// cell index + distances from v to the outer faces of the 3-cell box around it
__device__ __forceinline__ void axis_info(float v, int& c, float& blo, float& bhi) {
  float lom1 = -3e30f, lom2 = -3e30f, him1 = 3e30f, him2 = 3e30f;
  int cc = 0; bool b;
  b = v > GE0; cc += b; lom2 = b ? lom1 : lom2; lom1 = b ? GE0 : lom1;
  b = v > GE1; cc += b; lom2 = b ? lom1 : lom2; lom1 = b ? GE1 : lom1;
  b = v > GE2; cc += b; lom2 = b ? lom1 : lom2; lom1 = b ? GE2 : lom1;
  b = v > GE3; cc += b; lom2 = b ? lom1 : lom2; lom1 = b ? GE3 : lom1;
  b = v > GE4; cc += b; lom2 = b ? lom1 : lom2; lom1 = b ? GE4 : lom1;
  b = v > GE5; cc += b; lom2 = b ? lom1 : lom2; lom1 = b ? GE5 : lom1;
  b = v > GE6; cc += b; lom2 = b ? lom1 : lom2; lom1 = b ? GE6 : lom1;
  b = v > GE7; cc += b; lom2 = b ? lom1 : lom2; lom1 = b ? GE7 : lom1;
  b = v > GE8; cc += b; lom2 = b ? lom1 : lom2; lom1 = b ? GE8 : lom1;
  b = !(v > GE8); him2 = b ? him1 : him2; him1 = b ? GE8 : him1;
  b = !(v > GE7); him2 = b ? him1 : him2; him1 = b ? GE7 : him1;
  b = !(v > GE6); him2 = b ? him1 : him2; him1 = b ? GE6 : him1;
  b = !(v > GE5); him2 = b ? him1 : him2; him1 = b ? GE5 : him1;
  b = !(v > GE4); him2 = b ? him1 : him2; him1 = b ? GE4 : him1;
  b = !(v > GE3); him2 = b ? him1 : him2; him1 = b ? GE3 : him1;
  b = !(v > GE2); him2 = b ? him1 : him2; him1 = b ? GE2 : him1;
  b = !(v > GE1); him2 = b ? him1 : him2; him1 = b ? GE1 : him1;
  b = !(v > GE0); him2 = b ? him1 : him2; him1 = b ? GE0 : him1;
  c = cc; blo = v - lom2; bhi = him2 - v;   // E[c-2], E[c+1] faces (inf-safe)
}

// =================== prep: tpose + packs + GRID BUILD (block 578) ===================
__global__ __launch_bounds__(256) void pnfp_prep(
    const float* __restrict__ xyz2, const float* __restrict__ points2,
    const float* __restrict__ w0, const float* __restrict__ b0,
    const float* __restrict__ scale0, const float* __restrict__ bias0,
    const float* __restrict__ mean0, const float* __restrict__ var0,
    const float* __restrict__ w1, const float* __restrict__ b1,
    const float* __restrict__ scale1, const float* __restrict__ bias1,
    const float* __restrict__ mean1, const float* __restrict__ var1,
    unsigned char* __restrict__ ws)
{
  __shared__ __align__(16) unsigned char psh[49152];
  const int tid = threadIdx.x;

  if (blockIdx.x < 128) {             // transpose points2 -> p2t bf16
    float (*tile)[65] = (float(*)[65])psh;
    const int st = blockIdx.x & 31, dt = blockIdx.x >> 5;
#pragma unroll
    for (int it = 0; it < 16; ++it) {
      int j = it * 256 + tid;
      int d = j >> 6, s = j & 63;
      tile[d][s] = points2[(dt * 64 + d) * NS + st * 64 + s];
    }
    __syncthreads();
    unsigned short* p2t = (unsigned short*)(ws + WS_P2T);
#pragma unroll
    for (int it = 0; it < 16; ++it) {
      int j = it * 256 + tid;
      int s = j >> 6, d = j & 63;
      p2t[(st * 64 + s) * 256 + dt * 64 + d] = f2bf(tile[d][s]);
    }
    return;
  }

  if (blockIdx.x == 578) {            // ---- grid build (single block) ----
    float4* cbuf = (float4*)psh;                          // [2048]
    unsigned short* cellid = (unsigned short*)(psh + 32768); // [2048]
    unsigned* A  = (unsigned*)(psh + 36864);              // [1024]
    unsigned* B  = (unsigned*)(psh + 40960);              // [1024]
    unsigned* og = (unsigned*)(psh + 45056);              // [1024]
    for (int i = tid; i < 1024; i += 256) A[i] = 0;
    __syncthreads();
#pragma unroll
    for (int k = 0; k < 8; ++k) {
      int j = tid + k * 256;
      float x = xyz2[j], y = xyz2[NS + j], z = xyz2[2 * NS + j];
      float sc;
      {
#pragma clang fp contract(off)
        sc = (x * x + y * y) + z * z;
      }
      cbuf[j] = make_float4(x, y, z, sc);
      int cell = (cls9(z) * 10 + cls9(y)) * 10 + cls9(x);
      cellid[j] = (unsigned short)cell;
      atomicAdd(&A[cell], 1u);
    }
    __syncthreads();
    for (int i = tid; i < 1024; i += 256) og[i] = A[i];
    __syncthreads();
    unsigned* src = A; unsigned* dst = B;
    for (int off = 1; off < 1024; off <<= 1) {
#pragma unroll
      for (int k = 0; k < 4; ++k) {
        int i = tid + k * 256;
        unsigned v = src[i];
        if (i >= off) v += src[i - off];
        dst[i] = v;
      }
      __syncthreads();
      unsigned* t = src; src = dst; dst = t;
    }
    // src holds inclusive scan
    unsigned short* cst = (unsigned short*)(ws + WS_CSTART);
    for (int i = tid; i <= 1000; i += 256)
      cst[i] = (i == 0) ? 0 : (unsigned short)src[i - 1];
    for (int i = tid; i < 1024; i += 256) og[i] = src[i] - og[i];  // exclusive base
    __syncthreads();
    float4* so = (float4*)(ws + WS_SORT);
    unsigned short* sid = (unsigned short*)(ws + WS_SIDX);
#pragma unroll
    for (int k = 0; k < 8; ++k) {
      int j = tid + k * 256;
      int cell = cellid[j];
      unsigned pos = atomicAdd(&og[cell], 1u);
      so[pos] = cbuf[j];
      sid[pos] = (unsigned short)j;
    }
    if (tid == 0) *(unsigned*)(ws + WS_FCNT) = 0u;
    return;
  }

  int gid = ((int)blockIdx.x - 128) * 256 + tid;
  if (gid < 81920) {                  // W0 -> fragment-linear bf16
    int i = gid & 7, l = (gid >> 3) & 63, c = (gid >> 9) & 15, ks = gid >> 13;
    int k = ks * 32 + (l >> 4) * 8 + i;
    int col = c * 16 + (l & 15);
    ((unsigned short*)(ws + WS_W0F))[gid] = f2bf(w0[k * C2 + col]);
    return;
  }
  gid -= 81920;
  if (gid < 32768) {                  // W1 -> fragment-linear bf16
    int i = gid & 7, l = (gid >> 3) & 63, c = (gid >> 9) & 7, ks = gid >> 12;
    int k = ks * 32 + (l >> 4) * 8 + i;
    int col = c * 16 + (l & 15);
    ((unsigned short*)(ws + WS_W1F))[gid] = f2bf(w1[k * C3 + col]);
    return;
  }
  gid -= 32768;
  if (gid < 256) {
    float a = scale0[gid] / sqrtf(var0[gid] + 1e-5f);
    float bb = (b0[gid] - mean0[gid]) * a + bias0[gid];
    float* ab = (float*)(ws + WS_AB0);
    ab[gid] = a; ab[256 + gid] = bb;
    return;
  }
  gid -= 256;
  if (gid < 128) {
    float a = scale1[gid] / sqrtf(var1[gid] + 1e-5f);
    float bb = (b1[gid] - mean1[gid]) * a + bias1[gid];
    float* ab = (float*)(ws + WS_AB1);
    ab[gid] = a; ab[128 + gid] = bb;
  }
}

// =================== grid KNN: 27-cell exact scan, 1 thread/point ===================
// Tie-aware insert (d,idx) lexicographic => scan-order independent, matches
// top_k's lowest-index tie rule. Accept iff d3 <= bound^2 (bound = distance to
// the 3x3x3 box complement, edge cells infinite); else fallback list.
__global__ __launch_bounds__(128, 2) void pnfp_knn_grid(
    const float* __restrict__ xyz1, unsigned char* __restrict__ ws)
{
  __shared__ __align__(16) unsigned char sh[38880];
  float4* scs = (float4*)sh;                              // [2048]
  unsigned short* sidx = (unsigned short*)(sh + 32768);   // [2048]
  unsigned short* cst  = (unsigned short*)(sh + 36864);   // [1001]
  const int tid = threadIdx.x;
  for (int j = tid; j < 2048; j += 128) {
    scs[j] = ((const float4*)(ws + WS_SORT))[j];
    sidx[j] = ((const unsigned short*)(ws + WS_SIDX))[j];
  }
  for (int i = tid; i <= 1000; i += 128)
    cst[i] = ((const unsigned short*)(ws + WS_CSTART))[i];
  __syncthreads();

  const int n = blockIdx.x * 128 + tid;
  const float x = xyz1[n], y = xyz1[NPTS + n], z = xyz1[2 * NPTS + n];
  float ps;
  {
#pragma clang fp contract(off)
    ps = (x * x + y * y) + z * z;
  }
  int cx, cy, cz; float bxl, bxh, byl, byh, bzl, bzh;
  axis_info(x, cx, bxl, bxh);
  axis_info(y, cy, byl, byh);
  axis_info(z, cz, bzl, bzh);
  float bnd = fminf(fminf(fminf(bxl, bxh), fminf(byl, byh)), fminf(bzl, bzh));
  const float bnd2 = bnd * bnd * 0.999f;

  float D0 = 1e30f, D1 = 1e30f, D2 = 1e30f;
  int I0 = 0, I1 = 0, I2 = 0;
  const int zlo = max(cz - 1, 0), zhi = min(cz + 1, 9);
  const int ylo = max(cy - 1, 0), yhi = min(cy + 1, 9);
  const int xlo = max(cx - 1, 0), xhi = min(cx + 1, 9);
  for (int zz = zlo; zz <= zhi; ++zz)
    for (int yy = ylo; yy <= yhi; ++yy) {
      const int cb = (zz * 10 + yy) * 10;
      const int j0 = cst[cb + xlo], j1 = cst[cb + xhi + 1];  // x-cells contiguous
      for (int j = j0; j < j1; ++j) {
        float4 c = scs[j];
        int s = sidx[j];
        float dot = fmaf(z, c.z, fmaf(y, c.y, x * c.x));
        float d = (ps + c.w) - 2.0f * dot;
        bool c0 = (d < D0) || ((d == D0) && (s < I0));
        bool c1 = (d < D1) || ((d == D1) && (s < I1));
        bool c2 = (d < D2) || ((d == D2) && (s < I2));
        int nI0 = c0 ? s : I0;
        int nI1 = c0 ? I0 : (c1 ? s : I1);
        int nI2 = c1 ? I1 : (c2 ? s : I2);
        float nD1 = __builtin_amdgcn_fmed3f(D0, D1, d);
        float nD2 = __builtin_amdgcn_fmed3f(D1, D2, d);
        D0 = fminf(D0, d); D1 = nD1; D2 = nD2;
        I0 = nI0; I1 = nI1; I2 = nI2;
      }
    }

  if (D2 <= bnd2) {
    float q0 = 1.0f / (D0 + 1e-8f);
    float q1 = 1.0f / (D1 + 1e-8f);
    float q2 = 1.0f / (D2 + 1e-8f);
    float qs = (q0 + q1) + q2;
    int* oi = (int*)(ws + WS_KIDX) + 3 * n;
    float* owp = (float*)(ws + WS_KW) + 3 * n;
    oi[0] = I0; oi[1] = I1; oi[2] = I2;
    owp[0] = q0 / qs; owp[1] = q1 / qs; owp[2] = q2 / qs;
  } else {
    unsigned pos = atomicAdd((unsigned*)(ws + WS_FCNT), 1u);
    ((int*)(ws + WS_FLIST))[pos] = n;
  }
}

// =================== fallback: wave-per-point full 2048 scan ===================
__global__ __launch_bounds__(256) void pnfp_knn_fb(
    const float* __restrict__ xyz1, const float* __restrict__ xyz2,
    unsigned char* __restrict__ ws)
{
  __shared__ float4 cs[2176];         // 64 strips * 34 (4-way alias max)
  const int tid = threadIdx.x;
  for (int j = tid; j < NS; j += 256) {
    float x = xyz2[j], y = xyz2[NS + j], z = xyz2[2 * NS + j];
    float sc;
    {
#pragma clang fp contract(off)
      sc = (x * x + y * y) + z * z;
    }
    cs[(j >> 5) * 34 + (j & 31)] = make_float4(x, y, z, sc);
  }
  __syncthreads();
  const int lane = tid & 63;
  const int wv = (blockIdx.x << 2) | (tid >> 6);
  const unsigned cnt = *(const unsigned*)(ws + WS_FCNT);
  const float4* cq = cs + lane * 34;
  const int sbase = lane << 5;
  for (unsigned it = wv; it < cnt; it += 256) {
    const int n = ((const int*)(ws + WS_FLIST))[it];
    const float x = xyz1[n], y = xyz1[NPTS + n], z = xyz1[2 * NPTS + n];
    float ps;
    {
#pragma clang fp contract(off)
      ps = (x * x + y * y) + z * z;
    }
    float D0 = 1e30f, D1 = 1e30f, D2 = 1e30f;
    int I0 = 0, I1 = 0, I2 = 0;
#pragma unroll 4
    for (int t = 0; t < 32; ++t) {
      float4 c = cq[t];
      const int s = sbase + t;
      float dot = fmaf(z, c.z, fmaf(y, c.y, x * c.x));
      float d = (ps + c.w) - 2.0f * dot;
      const bool c2b = d < D2, c1b = d < D1, c0b = d < D0;
      I2 = c2b ? (c1b ? I1 : s) : I2;
      I1 = c1b ? (c0b ? I0 : s) : I1;
      I0 = c0b ? s : I0;
      float n1 = __builtin_amdgcn_fmed3f(D0, D1, d);
      float n2 = __builtin_amdgcn_fmed3f(D1, D2, d);
      D0 = fminf(D0, d); D1 = n1; D2 = n2;
    }
#pragma unroll
    for (int m = 1; m <= 32; m <<= 1) {
      float e0 = __shfl_xor(D0, m), e1 = __shfl_xor(D1, m), e2 = __shfl_xor(D2, m);
      int  j0 = __shfl_xor(I0, m), j1 = __shfl_xor(I1, m), j2 = __shfl_xor(I2, m);
      bool t0 = e0 < D0;
      float r0 = t0 ? e0 : D0; int ri0 = t0 ? j0 : I0;
      float X0 = t0 ? D0 : D1, X1 = t0 ? D1 : D2;
      int  XI0 = t0 ? I0 : I1, XI1 = t0 ? I1 : I2;
      float Y0 = t0 ? e1 : e0, Y1v = t0 ? e2 : e1;
      int  YJ0 = t0 ? j1 : j0, YJ1 = t0 ? j2 : j1;
      bool t1 = Y0 < X0;
      float r1 = t1 ? Y0 : X0; int ri1 = t1 ? YJ0 : XI0;
      float X0b = t1 ? X0 : X1; int XI0b = t1 ? XI0 : XI1;
      float Y0b = t1 ? Y1v : Y0; int YJ0b = t1 ? YJ1 : YJ0;
      bool t2 = Y0b < X0b;
      float r2 = t2 ? Y0b : X0b; int ri2 = t2 ? YJ0b : XI0b;
      D0 = r0; D1 = r1; D2 = r2; I0 = ri0; I1 = ri1; I2 = ri2;
    }
    if (lane == 0) {
      float q0 = 1.0f / (D0 + 1e-8f);
      float q1 = 1.0f / (D1 + 1e-8f);
      float q2 = 1.0f / (D2 + 1e-8f);
      float qs = (q0 + q1) + q2;
      int* oi = (int*)(ws + WS_KIDX) + 3 * n;
      float* owp = (float*)(ws + WS_KW) + 3 * n;
      oi[0] = I0; oi[1] = I1; oi[2] = I2;
      owp[0] = q0 / qs; owp[1] = q1 / qs; owp[2] = q2 / qs;
    }
  }
}

// =================== fused interp + concat + MLP (unchanged, validated) ===================
__global__ __launch_bounds__(256, 3) void pnfp_fused(
    const float* __restrict__ points1,
    const unsigned char* __restrict__ ws,
    float* __restrict__ out)
{
  __shared__ __align__(16) unsigned char smem[43520];
  unsigned short* Fh = (unsigned short*)smem;                 // [64][328] bf16
  int*   kI = (int*)(smem + 41984);                           // [192]
  float* kW = (float*)(smem + 42752);                         // [192]
  const unsigned short* p2t = (const unsigned short*)(ws + WS_P2T);
  const unsigned short* w0f = (const unsigned short*)(ws + WS_W0F);
  const unsigned short* w1f = (const unsigned short*)(ws + WS_W1F);
  const float* ab0 = (const float*)(ws + WS_AB0);
  const float* ab1 = (const float*)(ws + WS_AB1);
  const int* kidx = (const int*)(ws + WS_KIDX);
  const float* kw = (const float*)(ws + WS_KW);

  const int tid = threadIdx.x;
  const int wv = tid >> 6, lane = tid & 63;
  const int n0 = blockIdx.x * 64;

  if (tid < 192) {
    kI[tid] = kidx[3 * n0 + tid];
    kW[tid] = kw[3 * n0 + tid];
  }
#pragma unroll
  for (int it = 0; it < 16; ++it) {
    int j = tid + it * 256;
    int d = j >> 6, r = j & 63;
    Fh[r * 328 + d] = f2bf(points1[d * NPTS + n0 + r]);
  }
  __syncthreads();
  {
    const int dbase = lane * 4;
#pragma unroll 4
    for (int rr = 0; rr < 16; ++rr) {
      const int r = wv * 16 + rr;
      const int a0 = kI[3 * r], a1 = kI[3 * r + 1], a2 = kI[3 * r + 2];
      const float w0 = kW[3 * r], w1 = kW[3 * r + 1], w2 = kW[3 * r + 2];
      uint2 u0 = *(const uint2*)(p2t + a0 * 256 + dbase);
      uint2 u1 = *(const uint2*)(p2t + a1 * 256 + dbase);
      uint2 u2 = *(const uint2*)(p2t + a2 * 256 + dbase);
      float f0 = fmaf(w2, bf2f(u2.x & 0xFFFFu), fmaf(w1, bf2f(u1.x & 0xFFFFu), w0 * bf2f(u0.x & 0xFFFFu)));
      float f1 = fmaf(w2, bf2f(u2.x >> 16),     fmaf(w1, bf2f(u1.x >> 16),     w0 * bf2f(u0.x >> 16)));
      float f2v = fmaf(w2, bf2f(u2.y & 0xFFFFu), fmaf(w1, bf2f(u1.y & 0xFFFFu), w0 * bf2f(u0.y & 0xFFFFu)));
      float f3 = fmaf(w2, bf2f(u2.y >> 16),     fmaf(w1, bf2f(u1.y >> 16),     w0 * bf2f(u0.y >> 16)));
      uint2 pk;
      pk.x = (unsigned)f2bf(f0) | ((unsigned)f2bf(f1) << 16);
      pk.y = (unsigned)f2bf(f2v) | ((unsigned)f2bf(f3) << 16);
      *(uint2*)(Fh + r * 328 + 64 + dbase) = pk;
    }
  }
  __syncthreads();

  f32x4 zero4 = {0.f, 0.f, 0.f, 0.f};
  f32x4 acc[4][4];
#pragma unroll
  for (int a = 0; a < 4; ++a)
#pragma unroll
    for (int b = 0; b < 4; ++b) acc[a][b] = zero4;

  const int arow = lane & 15;
  const int koff = (lane >> 4) * 8;
  bf16x8 bcur[4], bnxt[4];
#pragma unroll
  for (int ct = 0; ct < 4; ++ct)
    bcur[ct] = *(const bf16x8*)(w0f + ((wv * 4 + ct) * 64 + lane) * 8);
  for (int ks = 0; ks < 10; ++ks) {
#pragma unroll
    for (int ct = 0; ct < 4; ++ct)
      bnxt[ct] = *(const bf16x8*)(w0f + (((ks + 1) * 16 + wv * 4 + ct) * 64 + lane) * 8);
    bf16x8 af[4];
#pragma unroll
    for (int rt = 0; rt < 4; ++rt)
      af[rt] = *(const bf16x8*)(Fh + (rt * 16 + arow) * 328 + ks * 32 + koff);
#pragma unroll
    for (int ct = 0; ct < 4; ++ct)
#pragma unroll
      for (int rt = 0; rt < 4; ++rt)
        acc[rt][ct] = __builtin_amdgcn_mfma_f32_16x16x32_bf16(af[rt], bcur[ct], acc[rt][ct], 0, 0, 0);
#pragma unroll
    for (int ct = 0; ct < 4; ++ct) bcur[ct] = bnxt[ct];
  }
  __syncthreads();

  unsigned short* Y1 = (unsigned short*)smem;
#pragma unroll
  for (int ct = 0; ct < 4; ++ct) {
    const int c = wv * 64 + ct * 16 + arow;
    const float a = ab0[c], b = ab0[256 + c];
#pragma unroll
    for (int rt = 0; rt < 4; ++rt) {
      const int rbase = rt * 16 + (lane >> 4) * 4;
#pragma unroll
      for (int qi = 0; qi < 4; ++qi) {
        float yv = fmaxf(fmaf(acc[rt][ct][qi], a, b), 0.0f);
        Y1[(rbase + qi) * 264 + c] = f2bf(yv);
      }
    }
  }
  __syncthreads();

  f32x4 acc2[4][2];
#pragma unroll
  for (int a = 0; a < 4; ++a) { acc2[a][0] = zero4; acc2[a][1] = zero4; }
  bf16x8 b2cur[2], b2nxt[2];
#pragma unroll
  for (int ct = 0; ct < 2; ++ct)
    b2cur[ct] = *(const bf16x8*)(w1f + ((wv * 2 + ct) * 64 + lane) * 8);
  for (int ks = 0; ks < 8; ++ks) {
#pragma unroll
    for (int ct = 0; ct < 2; ++ct)
      b2nxt[ct] = *(const bf16x8*)(w1f + (((ks + 1) * 8 + wv * 2 + ct) * 64 + lane) * 8);
    bf16x8 af[4];
#pragma unroll
    for (int rt = 0; rt < 4; ++rt)
      af[rt] = *(const bf16x8*)(Y1 + (rt * 16 + arow) * 264 + ks * 32 + koff);
#pragma unroll
    for (int ct = 0; ct < 2; ++ct)
#pragma unroll
      for (int rt = 0; rt < 4; ++rt)
        acc2[rt][ct] = __builtin_amdgcn_mfma_f32_16x16x32_bf16(af[rt], b2cur[ct], acc2[rt][ct], 0, 0, 0);
#pragma unroll
    for (int ct = 0; ct < 2; ++ct) b2cur[ct] = b2nxt[ct];
  }
  __syncthreads();

  float* OUT = (float*)smem;
#pragma unroll
  for (int ct = 0; ct < 2; ++ct) {
    const int c = wv * 32 + ct * 16 + arow;
    const float a = ab1[c], b = ab1[128 + c];
#pragma unroll
    for (int rt = 0; rt < 4; ++rt) {
      const int rbase = rt * 16 + (lane >> 4) * 4;
#pragma unroll
      for (int qi = 0; qi < 4; ++qi)
        OUT[c * 67 + rbase + qi] = fmaxf(fmaf(acc2[rt][ct][qi], a, b), 0.0f);
    }
  }
  __syncthreads();
#pragma unroll
  for (int it = 0; it < 32; ++it) {
    int j = tid + it * 256;
    int c = j >> 6, n = j & 63;
    out[c * NPTS + n0 + n] = OUT[c * 67 + n];
  }
}

// =================== host launcher ===================
extern "C" void kernel_launch(void* const* d_in, const int* in_sizes, int n_in,
                              void* d_out, int out_size, void* d_ws, size_t ws_size,
                              hipStream_t stream) {
  (void)in_sizes; (void)n_in; (void)out_size; (void)ws_size;
  const float* xyz1    = (const float*)d_in[0];
  const float* xyz2    = (const float*)d_in[1];
  const float* points1 = (const float*)d_in[2];
  const float* points2 = (const float*)d_in[3];
  const float* w0      = (const float*)d_in[4];
  const float* b0      = (const float*)d_in[5];
  const float* scale0  = (const float*)d_in[6];
  const float* bias0   = (const float*)d_in[7];
  const float* mean0   = (const float*)d_in[8];
  const float* var0    = (const float*)d_in[9];
  const float* w1      = (const float*)d_in[10];
  const float* b1      = (const float*)d_in[11];
  const float* scale1  = (const float*)d_in[12];
  const float* bias1   = (const float*)d_in[13];
  const float* mean1   = (const float*)d_in[14];
  const float* var1    = (const float*)d_in[15];
  unsigned char* ws = (unsigned char*)d_ws;
  float* out = (float*)d_out;

  pnfp_prep<<<579, 256, 0, stream>>>(xyz2, points2, w0, b0, scale0, bias0, mean0, var0,
                                     w1, b1, scale1, bias1, mean1, var1, ws);
  pnfp_knn_grid<<<512, 128, 0, stream>>>(xyz1, ws);
  pnfp_knn_fb<<<64, 256, 0, stream>>>(xyz1, xyz2, ws);
  pnfp_fused<<<1024, 256, 0, stream>>>(points1, ws, out);
}

// Round 8
// 205.822 us; speedup vs baseline: 1.8698x; 1.8698x over previous
//
#include <hip/hip_runtime.h>
#include <math.h>

#define NPTS 65536
#define NS   2048
#define C2   256
#define C3   128

// ---- workspace layout (byte offsets) ----
#define WS_SORT    0          // float4[2048] grid-sorted centres (x,y,z,|c|^2) : 32768
#define WS_P2T     32768      // bf16 [2048][256]          : 1048576
#define WS_W0F     1081344    // bf16 frag [10][16][64][8] : 163840
#define WS_W1F     1245184    // bf16 frag [8][8][64][8]   : 65536
#define WS_AB0     1310720    // float A0[256],B0[256]
#define WS_AB1     1312768    // float A1[128],B1[128]
#define WS_KIDX    1313792    // int [65536][3]
#define WS_KW      2100224    // float [65536][3]
#define WS_CSTART  2886656    // u16[217] CSR starts
#define WS_SIDX    2888704    // u16[2048] sorted->orig idx
#define WS_FCNT    2892800    // u32 fallback count
#define WS_FLIST   2892816    // int[65536] fallback point ids

typedef __attribute__((ext_vector_type(8))) short bf16x8;
typedef __attribute__((ext_vector_type(4))) float f32x4;

__device__ __forceinline__ unsigned short f2bf(float f) {
  unsigned u = __builtin_bit_cast(unsigned, f);
  u = (u + 0x7FFFu + ((u >> 16) & 1u)) >> 16;
  return (unsigned short)u;
}
__device__ __forceinline__ float bf2f(unsigned h) {
  return __builtin_bit_cast(float, h << 16);
}

// Gaussian sextile edges (build & query use the SAME constants, so partition
// exactness is independent of their values).
#define GF0 -0.96742157f
#define GF1 -0.43072730f
#define GF2  0.0f
#define GF3  0.43072730f
#define GF4  0.96742157f

__device__ __forceinline__ int cls6(float v) {
  int c = 0;
  c += v > GF0; c += v > GF1; c += v > GF2; c += v > GF3; c += v > GF4;
  return c;
}
// cell index + distances from v to the outer faces of its 3-cell box
__device__ __forceinline__ void axis_info6(float v, int& c, float& blo, float& bhi) {
  float lom1 = -3e30f, lom2 = -3e30f, him1 = 3e30f, him2 = 3e30f;
  int cc = 0; bool b;
  b = v > GF0; cc += b; lom2 = b ? lom1 : lom2; lom1 = b ? GF0 : lom1;
  b = v > GF1; cc += b; lom2 = b ? lom1 : lom2; lom1 = b ? GF1 : lom1;
  b = v > GF2; cc += b; lom2 = b ? lom1 : lom2; lom1 = b ? GF2 : lom1;
  b = v > GF3; cc += b; lom2 = b ? lom1 : lom2; lom1 = b ? GF3 : lom1;
  b = v > GF4; cc += b; lom2 = b ? lom1 : lom2; lom1 = b ? GF4 : lom1;
  b = !(v > GF4); him2 = b ? him1 : him2; him1 = b ? GF4 : him1;
  b = !(v > GF3); him2 = b ? him1 : him2; him1 = b ? GF3 : him1;
  b = !(v > GF2); him2 = b ? him1 : him2; him1 = b ? GF2 : him1;
  b = !(v > GF1); him2 = b ? him1 : him2; him1 = b ? GF1 : him1;
  b = !(v > GF0); him2 = b ? him1 : him2; him1 = b ? GF0 : him1;
  c = cc; blo = v - lom2; bhi = him2 - v;
}

// =================== prep: tpose + packs + GRID BUILD (block 578) ===================
__global__ __launch_bounds__(256) void pnfp_prep(
    const float* __restrict__ xyz2, const float* __restrict__ points2,
    const float* __restrict__ w0, const float* __restrict__ b0,
    const float* __restrict__ scale0, const float* __restrict__ bias0,
    const float* __restrict__ mean0, const float* __restrict__ var0,
    const float* __restrict__ w1, const float* __restrict__ b1,
    const float* __restrict__ scale1, const float* __restrict__ bias1,
    const float* __restrict__ mean1, const float* __restrict__ var1,
    unsigned char* __restrict__ ws)
{
  __shared__ __align__(16) unsigned char psh[49152];
  const int tid = threadIdx.x;

  if (blockIdx.x < 128) {             // transpose points2 -> p2t bf16
    float (*tile)[65] = (float(*)[65])psh;
    const int st = blockIdx.x & 31, dt = blockIdx.x >> 5;
#pragma unroll
    for (int it = 0; it < 16; ++it) {
      int j = it * 256 + tid;
      int d = j >> 6, s = j & 63;
      tile[d][s] = points2[(dt * 64 + d) * NS + st * 64 + s];
    }
    __syncthreads();
    unsigned short* p2t = (unsigned short*)(ws + WS_P2T);
#pragma unroll
    for (int it = 0; it < 16; ++it) {
      int j = it * 256 + tid;
      int s = j >> 6, d = j & 63;
      p2t[(st * 64 + s) * 256 + dt * 64 + d] = f2bf(tile[d][s]);
    }
    return;
  }

  if (blockIdx.x == 578) {            // ---- grid build (single block, 216 cells) ----
    float4* cbuf = (float4*)psh;                             // [2048] : 32768
    unsigned short* cellid = (unsigned short*)(psh + 32768); // [2048] : 4096
    unsigned* A  = (unsigned*)(psh + 36864);                 // [256]
    unsigned* B  = (unsigned*)(psh + 37888);                 // [256]
    unsigned* og = (unsigned*)(psh + 38912);                 // [256]
    A[tid] = 0;
    __syncthreads();
#pragma unroll
    for (int k = 0; k < 8; ++k) {
      int j = tid + k * 256;
      float x = xyz2[j], y = xyz2[NS + j], z = xyz2[2 * NS + j];
      float sc;
      {
#pragma clang fp contract(off)
        sc = (x * x + y * y) + z * z;
      }
      cbuf[j] = make_float4(x, y, z, sc);
      int cell = (cls6(z) * 6 + cls6(y)) * 6 + cls6(x);
      cellid[j] = (unsigned short)cell;
      atomicAdd(&A[cell], 1u);
    }
    __syncthreads();
    og[tid] = A[tid];
    __syncthreads();
    unsigned* src = A; unsigned* dst = B;
    for (int off = 1; off < 256; off <<= 1) {
      unsigned v = src[tid];
      if (tid >= off) v += src[tid - off];
      dst[tid] = v;
      __syncthreads();
      unsigned* t = src; src = dst; dst = t;
    }
    // src holds inclusive scan
    unsigned short* cst = (unsigned short*)(ws + WS_CSTART);
    if (tid <= 216) cst[tid] = (tid == 0) ? 0 : (unsigned short)src[tid - 1];
    og[tid] = src[tid] - og[tid];     // exclusive base
    __syncthreads();
    float4* so = (float4*)(ws + WS_SORT);
    unsigned short* sid = (unsigned short*)(ws + WS_SIDX);
#pragma unroll
    for (int k = 0; k < 8; ++k) {
      int j = tid + k * 256;
      int cell = cellid[j];
      unsigned pos = atomicAdd(&og[cell], 1u);
      so[pos] = cbuf[j];
      sid[pos] = (unsigned short)j;
    }
    if (tid == 0) *(unsigned*)(ws + WS_FCNT) = 0u;
    return;
  }

  int gid = ((int)blockIdx.x - 128) * 256 + tid;
  if (gid < 81920) {                  // W0 -> fragment-linear bf16
    int i = gid & 7, l = (gid >> 3) & 63, c = (gid >> 9) & 15, ks = gid >> 13;
    int k = ks * 32 + (l >> 4) * 8 + i;
    int col = c * 16 + (l & 15);
    ((unsigned short*)(ws + WS_W0F))[gid] = f2bf(w0[k * C2 + col]);
    return;
  }
  gid -= 81920;
  if (gid < 32768) {                  // W1 -> fragment-linear bf16
    int i = gid & 7, l = (gid >> 3) & 63, c = (gid >> 9) & 7, ks = gid >> 12;
    int k = ks * 32 + (l >> 4) * 8 + i;
    int col = c * 16 + (l & 15);
    ((unsigned short*)(ws + WS_W1F))[gid] = f2bf(w1[k * C3 + col]);
    return;
  }
  gid -= 32768;
  if (gid < 256) {
    float a = scale0[gid] / sqrtf(var0[gid] + 1e-5f);
    float bb = (b0[gid] - mean0[gid]) * a + bias0[gid];
    float* ab = (float*)(ws + WS_AB0);
    ab[gid] = a; ab[256 + gid] = bb;
    return;
  }
  gid -= 256;
  if (gid < 128) {
    float a = scale1[gid] / sqrtf(var1[gid] + 1e-5f);
    float bb = (b1[gid] - mean1[gid]) * a + bias1[gid];
    float* ab = (float*)(ws + WS_AB1);
    ab[gid] = a; ab[128 + gid] = bb;
  }
}

// =================== grid KNN: 27-cell exact scan, 4 threads/point ===================
// Threads of a quad interleave j+=4 within each contiguous x-row, so all lanes
// work simultaneously. Lexicographic (d,idx) insert & merge => scan-order
// independent, exactly matching top_k's lowest-index tie rule. Accept iff
// d3 <= bound^2 (bound = distance to the 3x3x3 cell-box complement).
__global__ __launch_bounds__(256) void pnfp_knn_grid(
    const float* __restrict__ xyz1, unsigned char* __restrict__ ws)
{
  __shared__ __align__(16) float4 scs[2048];
  __shared__ unsigned short sidx[2048];
  __shared__ unsigned short cst[218];
  const int tid = threadIdx.x;
  for (int j = tid; j < 2048; j += 256) {
    scs[j] = ((const float4*)(ws + WS_SORT))[j];
    sidx[j] = ((const unsigned short*)(ws + WS_SIDX))[j];
  }
  if (tid <= 216) cst[tid] = ((const unsigned short*)(ws + WS_CSTART))[tid];
  __syncthreads();

  const int q = tid & 3;
  const int n = blockIdx.x * 64 + (tid >> 2);
  const float x = xyz1[n], y = xyz1[NPTS + n], z = xyz1[2 * NPTS + n];
  float ps;
  {
#pragma clang fp contract(off)
    ps = (x * x + y * y) + z * z;
  }
  int cx, cy, cz; float bxl, bxh, byl, byh, bzl, bzh;
  axis_info6(x, cx, bxl, bxh);
  axis_info6(y, cy, byl, byh);
  axis_info6(z, cz, bzl, bzh);
  float bnd = fminf(fminf(fminf(bxl, bxh), fminf(byl, byh)), fminf(bzl, bzh));
  const float bnd2 = bnd * bnd * 0.999f;

  float D0 = 1e30f, D1 = 1e30f, D2 = 1e30f;
  int I0 = 0, I1 = 0, I2 = 0;
  const int zlo = max(cz - 1, 0), zhi = min(cz + 1, 5);
  const int ylo = max(cy - 1, 0), yhi = min(cy + 1, 5);
  const int xlo = max(cx - 1, 0), xhi = min(cx + 1, 5);
  for (int zz = zlo; zz <= zhi; ++zz)
    for (int yy = ylo; yy <= yhi; ++yy) {
      const int cb = (zz * 6 + yy) * 6;
      const int j0 = cst[cb + xlo], j1 = cst[cb + xhi + 1];  // x-cells contiguous
      for (int j = j0 + q; j < j1; j += 4) {
        float4 c = scs[j];
        int s = sidx[j];
        float dot = fmaf(z, c.z, fmaf(y, c.y, x * c.x));
        float d = (ps + c.w) - 2.0f * dot;
        bool c0 = (d < D0) || ((d == D0) && (s < I0));
        bool c1 = (d < D1) || ((d == D1) && (s < I1));
        bool c2 = (d < D2) || ((d == D2) && (s < I2));
        int nI0 = c0 ? s : I0;
        int nI1 = c0 ? I0 : (c1 ? s : I1);
        int nI2 = c1 ? I1 : (c2 ? s : I2);
        float nD1 = __builtin_amdgcn_fmed3f(D0, D1, d);
        float nD2 = __builtin_amdgcn_fmed3f(D1, D2, d);
        D0 = fminf(D0, d); D1 = nD1; D2 = nD2;
        I0 = nI0; I1 = nI1; I2 = nI2;
      }
    }

  // 2 lexicographic merge stages within the quad (total order => exact)
#pragma unroll
  for (int m = 1; m <= 2; m <<= 1) {
    float e0 = __shfl_xor(D0, m), e1 = __shfl_xor(D1, m), e2 = __shfl_xor(D2, m);
    int  j0 = __shfl_xor(I0, m), j1 = __shfl_xor(I1, m), j2 = __shfl_xor(I2, m);
    bool t0 = (e0 < D0) || ((e0 == D0) && (j0 < I0));
    float r0 = t0 ? e0 : D0; int ri0 = t0 ? j0 : I0;
    float X0 = t0 ? D0 : D1, X1 = t0 ? D1 : D2;
    int  XI0 = t0 ? I0 : I1, XI1 = t0 ? I1 : I2;
    float Y0 = t0 ? e1 : e0, Y1v = t0 ? e2 : e1;
    int  YJ0 = t0 ? j1 : j0, YJ1 = t0 ? j2 : j1;
    bool t1 = (Y0 < X0) || ((Y0 == X0) && (YJ0 < XI0));
    float r1 = t1 ? Y0 : X0; int ri1 = t1 ? YJ0 : XI0;
    float X0b = t1 ? X0 : X1; int XI0b = t1 ? XI0 : XI1;
    float Y0b = t1 ? Y1v : Y0; int YJ0b = t1 ? YJ1 : YJ0;
    bool t2 = (Y0b < X0b) || ((Y0b == X0b) && (YJ0b < XI0b));
    float r2 = t2 ? Y0b : X0b; int ri2 = t2 ? YJ0b : XI0b;
    D0 = r0; D1 = r1; D2 = r2; I0 = ri0; I1 = ri1; I2 = ri2;
  }

  if (q == 0) {
    if (D2 <= bnd2) {
      float q0 = 1.0f / (D0 + 1e-8f);
      float q1 = 1.0f / (D1 + 1e-8f);
      float q2 = 1.0f / (D2 + 1e-8f);
      float qs = (q0 + q1) + q2;
      int* oi = (int*)(ws + WS_KIDX) + 3 * n;
      float* owp = (float*)(ws + WS_KW) + 3 * n;
      oi[0] = I0; oi[1] = I1; oi[2] = I2;
      owp[0] = q0 / qs; owp[1] = q1 / qs; owp[2] = q2 / qs;
    } else {
      unsigned pos = atomicAdd((unsigned*)(ws + WS_FCNT), 1u);
      ((int*)(ws + WS_FLIST))[pos] = n;
    }
  }
}

// =================== fallback: wave-per-point full 2048 scan ===================
__global__ __launch_bounds__(256) void pnfp_knn_fb(
    const float* __restrict__ xyz1, const float* __restrict__ xyz2,
    unsigned char* __restrict__ ws)
{
  __shared__ float4 cs[2112];         // 64 strips * 33 (Delta-4-dword starts: conflict-free)
  const int tid = threadIdx.x;
  for (int j = tid; j < NS; j += 256) {
    float x = xyz2[j], y = xyz2[NS + j], z = xyz2[2 * NS + j];
    float sc;
    {
#pragma clang fp contract(off)
      sc = (x * x + y * y) + z * z;
    }
    cs[(j >> 5) * 33 + (j & 31)] = make_float4(x, y, z, sc);
  }
  __syncthreads();
  const int lane = tid & 63;
  const int wv = (blockIdx.x << 2) | (tid >> 6);
  const unsigned cnt = *(const unsigned*)(ws + WS_FCNT);
  const float4* cq = cs + lane * 33;
  const int sbase = lane << 5;
  for (unsigned it = wv; it < cnt; it += 1024) {
    const int n = ((const int*)(ws + WS_FLIST))[it];
    const float x = xyz1[n], y = xyz1[NPTS + n], z = xyz1[2 * NPTS + n];
    float ps;
    {
#pragma clang fp contract(off)
      ps = (x * x + y * y) + z * z;
    }
    float D0 = 1e30f, D1 = 1e30f, D2 = 1e30f;
    int I0 = 0, I1 = 0, I2 = 0;
#pragma unroll 4
    for (int t = 0; t < 32; ++t) {
      float4 c = cq[t];
      const int s = sbase + t;
      float dot = fmaf(z, c.z, fmaf(y, c.y, x * c.x));
      float d = (ps + c.w) - 2.0f * dot;
      const bool c2b = d < D2, c1b = d < D1, c0b = d < D0;
      I2 = c2b ? (c1b ? I1 : s) : I2;
      I1 = c1b ? (c0b ? I0 : s) : I1;
      I0 = c0b ? s : I0;
      float n1 = __builtin_amdgcn_fmed3f(D0, D1, d);
      float n2 = __builtin_amdgcn_fmed3f(D1, D2, d);
      D0 = fminf(D0, d); D1 = n1; D2 = n2;
    }
#pragma unroll
    for (int m = 1; m <= 32; m <<= 1) {
      float e0 = __shfl_xor(D0, m), e1 = __shfl_xor(D1, m), e2 = __shfl_xor(D2, m);
      int  j0 = __shfl_xor(I0, m), j1 = __shfl_xor(I1, m), j2 = __shfl_xor(I2, m);
      bool t0 = e0 < D0;
      float r0 = t0 ? e0 : D0; int ri0 = t0 ? j0 : I0;
      float X0 = t0 ? D0 : D1, X1 = t0 ? D1 : D2;
      int  XI0 = t0 ? I0 : I1, XI1 = t0 ? I1 : I2;
      float Y0 = t0 ? e1 : e0, Y1v = t0 ? e2 : e1;
      int  YJ0 = t0 ? j1 : j0, YJ1 = t0 ? j2 : j1;
      bool t1 = Y0 < X0;
      float r1 = t1 ? Y0 : X0; int ri1 = t1 ? YJ0 : XI0;
      float X0b = t1 ? X0 : X1; int XI0b = t1 ? XI0 : XI1;
      float Y0b = t1 ? Y1v : Y0; int YJ0b = t1 ? YJ1 : YJ0;
      bool t2 = Y0b < X0b;
      float r2 = t2 ? Y0b : X0b; int ri2 = t2 ? YJ0b : XI0b;
      D0 = r0; D1 = r1; D2 = r2; I0 = ri0; I1 = ri1; I2 = ri2;
    }
    if (lane == 0) {
      float q0 = 1.0f / (D0 + 1e-8f);
      float q1 = 1.0f / (D1 + 1e-8f);
      float q2 = 1.0f / (D2 + 1e-8f);
      float qs = (q0 + q1) + q2;
      int* oi = (int*)(ws + WS_KIDX) + 3 * n;
      float* owp = (float*)(ws + WS_KW) + 3 * n;
      oi[0] = I0; oi[1] = I1; oi[2] = I2;
      owp[0] = q0 / qs; owp[1] = q1 / qs; owp[2] = q2 / qs;
    }
  }
}

// =================== fused interp + concat + MLP (unchanged, validated) ===================
__global__ __launch_bounds__(256, 3) void pnfp_fused(
    const float* __restrict__ points1,
    const unsigned char* __restrict__ ws,
    float* __restrict__ out)
{
  __shared__ __align__(16) unsigned char smem[43520];
  unsigned short* Fh = (unsigned short*)smem;                 // [64][328] bf16
  int*   kI = (int*)(smem + 41984);                           // [192]
  float* kW = (float*)(smem + 42752);                         // [192]
  const unsigned short* p2t = (const unsigned short*)(ws + WS_P2T);
  const unsigned short* w0f = (const unsigned short*)(ws + WS_W0F);
  const unsigned short* w1f = (const unsigned short*)(ws + WS_W1F);
  const float* ab0 = (const float*)(ws + WS_AB0);
  const float* ab1 = (const float*)(ws + WS_AB1);
  const int* kidx = (const int*)(ws + WS_KIDX);
  const float* kw = (const float*)(ws + WS_KW);

  const int tid = threadIdx.x;
  const int wv = tid >> 6, lane = tid & 63;
  const int n0 = blockIdx.x * 64;

  if (tid < 192) {
    kI[tid] = kidx[3 * n0 + tid];
    kW[tid] = kw[3 * n0 + tid];
  }
#pragma unroll
  for (int it = 0; it < 16; ++it) {
    int j = tid + it * 256;
    int d = j >> 6, r = j & 63;
    Fh[r * 328 + d] = f2bf(points1[d * NPTS + n0 + r]);
  }
  __syncthreads();
  {
    const int dbase = lane * 4;
#pragma unroll 4
    for (int rr = 0; rr < 16; ++rr) {
      const int r = wv * 16 + rr;
      const int a0 = kI[3 * r], a1 = kI[3 * r + 1], a2 = kI[3 * r + 2];
      const float w0 = kW[3 * r], w1 = kW[3 * r + 1], w2 = kW[3 * r + 2];
      uint2 u0 = *(const uint2*)(p2t + a0 * 256 + dbase);
      uint2 u1 = *(const uint2*)(p2t + a1 * 256 + dbase);
      uint2 u2 = *(const uint2*)(p2t + a2 * 256 + dbase);
      float f0 = fmaf(w2, bf2f(u2.x & 0xFFFFu), fmaf(w1, bf2f(u1.x & 0xFFFFu), w0 * bf2f(u0.x & 0xFFFFu)));
      float f1 = fmaf(w2, bf2f(u2.x >> 16),     fmaf(w1, bf2f(u1.x >> 16),     w0 * bf2f(u0.x >> 16)));
      float f2v = fmaf(w2, bf2f(u2.y & 0xFFFFu), fmaf(w1, bf2f(u1.y & 0xFFFFu), w0 * bf2f(u0.y & 0xFFFFu)));
      float f3 = fmaf(w2, bf2f(u2.y >> 16),     fmaf(w1, bf2f(u1.y >> 16),     w0 * bf2f(u0.y >> 16)));
      uint2 pk;
      pk.x = (unsigned)f2bf(f0) | ((unsigned)f2bf(f1) << 16);
      pk.y = (unsigned)f2bf(f2v) | ((unsigned)f2bf(f3) << 16);
      *(uint2*)(Fh + r * 328 + 64 + dbase) = pk;
    }
  }
  __syncthreads();

  f32x4 zero4 = {0.f, 0.f, 0.f, 0.f};
  f32x4 acc[4][4];
#pragma unroll
  for (int a = 0; a < 4; ++a)
#pragma unroll
    for (int b = 0; b < 4; ++b) acc[a][b] = zero4;

  const int arow = lane & 15;
  const int koff = (lane >> 4) * 8;
  bf16x8 bcur[4], bnxt[4];
#pragma unroll
  for (int ct = 0; ct < 4; ++ct)
    bcur[ct] = *(const bf16x8*)(w0f + ((wv * 4 + ct) * 64 + lane) * 8);
  for (int ks = 0; ks < 10; ++ks) {
#pragma unroll
    for (int ct = 0; ct < 4; ++ct)
      bnxt[ct] = *(const bf16x8*)(w0f + (((ks + 1) * 16 + wv * 4 + ct) * 64 + lane) * 8);
    bf16x8 af[4];
#pragma unroll
    for (int rt = 0; rt < 4; ++rt)
      af[rt] = *(const bf16x8*)(Fh + (rt * 16 + arow) * 328 + ks * 32 + koff);
#pragma unroll
    for (int ct = 0; ct < 4; ++ct)
#pragma unroll
      for (int rt = 0; rt < 4; ++rt)
        acc[rt][ct] = __builtin_amdgcn_mfma_f32_16x16x32_bf16(af[rt], bcur[ct], acc[rt][ct], 0, 0, 0);
#pragma unroll
    for (int ct = 0; ct < 4; ++ct) bcur[ct] = bnxt[ct];
  }
  __syncthreads();

  unsigned short* Y1 = (unsigned short*)smem;
#pragma unroll
  for (int ct = 0; ct < 4; ++ct) {
    const int c = wv * 64 + ct * 16 + arow;
    const float a = ab0[c], b = ab0[256 + c];
#pragma unroll
    for (int rt = 0; rt < 4; ++rt) {
      const int rbase = rt * 16 + (lane >> 4) * 4;
#pragma unroll
      for (int qi = 0; qi < 4; ++qi) {
        float yv = fmaxf(fmaf(acc[rt][ct][qi], a, b), 0.0f);
        Y1[(rbase + qi) * 264 + c] = f2bf(yv);
      }
    }
  }
  __syncthreads();

  f32x4 acc2[4][2];
#pragma unroll
  for (int a = 0; a < 4; ++a) { acc2[a][0] = zero4; acc2[a][1] = zero4; }
  bf16x8 b2cur[2], b2nxt[2];
#pragma unroll
  for (int ct = 0; ct < 2; ++ct)
    b2cur[ct] = *(const bf16x8*)(w1f + ((wv * 2 + ct) * 64 + lane) * 8);
  for (int ks = 0; ks < 8; ++ks) {
#pragma unroll
    for (int ct = 0; ct < 2; ++ct)
      b2nxt[ct] = *(const bf16x8*)(w1f + (((ks + 1) * 8 + wv * 2 + ct) * 64 + lane) * 8);
    bf16x8 af[4];
#pragma unroll
    for (int rt = 0; rt < 4; ++rt)
      af[rt] = *(const bf16x8*)(Y1 + (rt * 16 + arow) * 264 + ks * 32 + koff);
#pragma unroll
    for (int ct = 0; ct < 2; ++ct)
#pragma unroll
      for (int rt = 0; rt < 4; ++rt)
        acc2[rt][ct] = __builtin_amdgcn_mfma_f32_16x16x32_bf16(af[rt], b2cur[ct], acc2[rt][ct], 0, 0, 0);
#pragma unroll
    for (int ct = 0; ct < 2; ++ct) b2cur[ct] = b2nxt[ct];
  }
  __syncthreads();

  float* OUT = (float*)smem;
#pragma unroll
  for (int ct = 0; ct < 2; ++ct) {
    const int c = wv * 32 + ct * 16 + arow;
    const float a = ab1[c], b = ab1[128 + c];
#pragma unroll
    for (int rt = 0; rt < 4; ++rt) {
      const int rbase = rt * 16 + (lane >> 4) * 4;
#pragma unroll
      for (int qi = 0; qi < 4; ++qi)
        OUT[c * 67 + rbase + qi] = fmaxf(fmaf(acc2[rt][ct][qi], a, b), 0.0f);
    }
  }
  __syncthreads();
#pragma unroll
  for (int it = 0; it < 32; ++it) {
    int j = tid + it * 256;
    int c = j >> 6, n = j & 63;
    out[c * NPTS + n0 + n] = OUT[c * 67 + n];
  }
}

// =================== host launcher ===================
extern "C" void kernel_launch(void* const* d_in, const int* in_sizes, int n_in,
                              void* d_out, int out_size, void* d_ws, size_t ws_size,
                              hipStream_t stream) {
  (void)in_sizes; (void)n_in; (void)out_size; (void)ws_size;
  const float* xyz1    = (const float*)d_in[0];
  const float* xyz2    = (const float*)d_in[1];
  const float* points1 = (const float*)d_in[2];
  const float* points2 = (const float*)d_in[3];
  const float* w0      = (const float*)d_in[4];
  const float* b0      = (const float*)d_in[5];
  const float* scale0  = (const float*)d_in[6];
  const float* bias0   = (const float*)d_in[7];
  const float* mean0   = (const float*)d_in[8];
  const float* var0    = (const float*)d_in[9];
  const float* w1      = (const float*)d_in[10];
  const float* b1      = (const float*)d_in[11];
  const float* scale1  = (const float*)d_in[12];
  const float* bias1   = (const float*)d_in[13];
  const float* mean1   = (const float*)d_in[14];
  const float* var1    = (const float*)d_in[15];
  unsigned char* ws = (unsigned char*)d_ws;
  float* out = (float*)d_out;

  pnfp_prep<<<579, 256, 0, stream>>>(xyz2, points2, w0, b0, scale0, bias0, mean0, var0,
                                     w1, b1, scale1, bias1, mean1, var1, ws);
  pnfp_knn_grid<<<1024, 256, 0, stream>>>(xyz1, ws);
  pnfp_knn_fb<<<256, 256, 0, stream>>>(xyz1, xyz2, ws);
  pnfp_fused<<<1024, 256, 0, stream>>>(points1, ws, out);
}